// Round 5
// baseline (6429.690 us; speedup 1.0000x reference)
//
#include <hip/hip_runtime.h>

#define N_NODES 100000
#define N_EDGES 3200000
#define N_IN    128
#define N_OUT   64
#define ITERS   150
#define LEAK    0.01f

#define NBW     254            // worker blocks (blocks 1..254); block 0 = detector
#define NBLK    (NBW + 1)
#define NT      1024
#define RPB     394            // ceil(N_NODES / NBW) rows per worker
#define NCH     8              // column chunks
#define CH      12544          // cols per chunk (50.2KB LDS buffer)
#define CHF4    (CH / 4)       // 3136
#define LASTF4  3048           // (100000 - 7*12544)/4
#define NKEYS   (NCH * N_NODES)
#define SCAN_CHUNK 1024
#define SCAN_NBLK  782         // 782*1024 >= NKEYS+1
#define NEPC    16             // replicated epoch copies per chunk-group
#define EPST    32             // ints between copies (128B)
#define YSTR    100096         // y buffer stride (float4-aligned)
#define NBUF    150

__device__ __forceinline__ float mml(float v) {
    v = (v < 0.0f) ? v * LEAK : v;
    if (v > 0.5f) v = 1.0f - 0.25f / v;
    return v;
}

__global__ void k_binit(const float* __restrict__ biases, float* __restrict__ b_in) {
    int i = blockIdx.x * blockDim.x + threadIdx.x;
    if (i < N_NODES) b_in[i] = biases[i];
}

// node_in.at[in_indices].set(in_w * x) -> last-write-wins for duplicates
__global__ void k_scatter_in(const float* __restrict__ x,
                             const float* __restrict__ in_w,
                             const int*   __restrict__ in_idx,
                             const float* __restrict__ biases,
                             float* __restrict__ b_in) {
    int k = threadIdx.x;
    if (k < N_IN) {
        int idx = in_idx[k];
        bool last = true;
        for (int j = k + 1; j < N_IN; ++j)
            if (in_idx[j] == idx) { last = false; break; }
        if (last) b_in[idx] = biases[idx] + in_w[k] * x[k];
    }
}

// y^(1) = act(0 + b_in)  (first reference iteration: A @ 0 == 0)
__global__ void k_y0(const float* __restrict__ b_in, float* __restrict__ y0) {
    int i = blockIdx.x * blockDim.x + threadIdx.x;
    if (i < N_NODES) y0[i] = mml(b_in[i]);
}

// histogram over (chunk, row) buckets: key = (col/CH)*N + row  (chunk-major ->
// each worker's per-chunk CSR slab is contiguous)
__global__ void k_hist(const int* __restrict__ rows, const int* __restrict__ cols,
                       int* __restrict__ counts) {
    int i = blockIdx.x * blockDim.x + threadIdx.x;
    int stride = gridDim.x * blockDim.x;
    for (; i < N_EDGES; i += stride) {
        int key = (cols[i] / CH) * N_NODES + rows[i];
        atomicAdd(&counts[key], 1);
    }
}

__global__ void k_scan1(const int* __restrict__ counts, int* __restrict__ rp,
                        int* __restrict__ blockSums) {
    __shared__ int sm[SCAN_CHUNK];
    int t = threadIdx.x;
    int i = blockIdx.x * SCAN_CHUNK + t;
    int v = (i < NKEYS) ? counts[i] : 0;
    sm[t] = v;
    __syncthreads();
    for (int off = 1; off < SCAN_CHUNK; off <<= 1) {
        int add = (t >= off) ? sm[t - off] : 0;
        __syncthreads();
        sm[t] += add;
        __syncthreads();
    }
    if (i <= NKEYS) rp[i] = sm[t] - v;
    if (t == SCAN_CHUNK - 1) blockSums[blockIdx.x] = sm[t];
}

__global__ void k_scan2(int* __restrict__ blockSums) {
    __shared__ int sm[1024];
    int t = threadIdx.x;
    int v = (t < SCAN_NBLK) ? blockSums[t] : 0;
    sm[t] = v;
    __syncthreads();
    for (int off = 1; off < 1024; off <<= 1) {
        int add = (t >= off) ? sm[t - off] : 0;
        __syncthreads();
        sm[t] += add;
        __syncthreads();
    }
    if (t < SCAN_NBLK) blockSums[t] = sm[t] - v;
}

__global__ void k_scan3(int* __restrict__ rp, const int* __restrict__ blockSums,
                        int* __restrict__ next) {
    int i = blockIdx.x * SCAN_CHUNK + threadIdx.x;
    if (i <= NKEYS) {
        int val = rp[i] + blockSums[blockIdx.x];
        rp[i] = val;
        if (i < NKEYS) next[i] = val;
    }
}

// fill bucketed edge list: (local_col_within_chunk, weight)
__global__ void k_scatter_edges(const int* __restrict__ rows, const int* __restrict__ cols,
                                const float* __restrict__ w,
                                int* __restrict__ next, int2* __restrict__ csr) {
    int i = blockIdx.x * blockDim.x + threadIdx.x;
    int stride = gridDim.x * blockDim.x;
    for (; i < N_EDGES; i += stride) {
        int c = cols[i];
        int g = c / CH;
        int key = g * N_NODES + rows[i];
        int p = atomicAdd(&next[key], 1);
        csr[p] = make_int2(c - g * CH, __float_as_int(w[i]));
    }
}

__device__ __forceinline__ void gate(int g, int it, int b, int t,
                                     const int* __restrict__ epoch,
                                     volatile int* s_rdy) {
    // chunk g of iteration it reads y^(it-1): need group-g producers arrived it-1
    if (t == 0) {
        const int c = b & (NEPC - 1);
        while (__hip_atomic_load(&epoch[(g * NEPC + c) * EPST], __ATOMIC_RELAXED,
                                 __HIP_MEMORY_SCOPE_AGENT) < it - 1)
            __builtin_amdgcn_s_sleep(1);
        s_rdy[g] = it;
    }
    while (s_rdy[g] < it) {}
}

// block 0 = detector: wave g polls group-g producer arrival slots; on all>=v
// (wave reconvergence aggregates), publishes v to 16 replicated epoch words.
// blocks 1..254 = workers: per iteration, 8-chunk double-buffered LDS pipeline
// with per-chunk release gates; only the chunk-0 wait is ever exposed.
__global__ __launch_bounds__(NT) void k_iterate(
    const int*  __restrict__ rp2,
    const int2* __restrict__ csr,
    const float* __restrict__ b_in,
    float* __restrict__ ybufs,
    int* __restrict__ arr,
    int* __restrict__ epoch,
    const int* __restrict__ out_idx,
    const float* __restrict__ out_w,
    float* __restrict__ out,
    int nbuf, int sc1mode)
{
    __shared__ float syA[CH], syB[CH];   // 2 x 50.2 KB
    __shared__ int s_rdy_s[NCH];
    volatile int* s_rdy = s_rdy_s;
    const int b = blockIdx.x, t = threadIdx.x;

    if (b == 0) {
        // ---------------- detector ----------------
        if (t < NCH * 64) {
            const int g = t >> 6, k = t & 63;
            const int c0 = g * CH;
            const int c1 = ((c0 + CH < N_NODES) ? c0 + CH : N_NODES) - 1;
            const int wf = c0 / RPB, wl = c1 / RPB;
            const int sz = wl - wf + 1;          // <= 33
            for (int v = 1; v <= ITERS - 1; ++v) {
                if (k < sz) {
                    while (__hip_atomic_load(&arr[wf + 1 + k], __ATOMIC_RELAXED,
                                             __HIP_MEMORY_SCOPE_AGENT) < v)
                        __builtin_amdgcn_s_sleep(2);
                }
                // wave reconverged: all active lanes saw arr >= v
                if (k < NEPC)
                    __hip_atomic_store(&epoch[(g * NEPC + k) * EPST], v,
                                       __ATOMIC_RELAXED, __HIP_MEMORY_SCOPE_AGENT);
            }
        }
        return;
    }

    // ---------------- worker ----------------
    const int wi = b - 1;
    const int row0 = wi * RPB;
    const int row_end = (row0 + RPB < N_NODES) ? row0 + RPB : N_NODES;
    const int gq = t >> 2, j = t & 3;            // 4 lanes per row
    const int r1 = row0 + gq;                    // always < row_end (256 <= 318)
    const int r2 = row0 + gq + 256;

    if (t < NCH) s_rdy_s[t] = 0;
    __syncthreads();

    for (int it = 1; it <= ITERS - 1; ++it) {
        const float* ysrc = ybufs + (size_t)((it - 1) % nbuf) * YSTR;
        float*       ydst = ybufs + (size_t)(it % nbuf) * YSTR;
        float acc1 = 0.f, acc2 = 0.f;

        // stage chunk 0 -> syA
        gate(0, it, b, t, epoch, s_rdy);
        if (!sc1mode) {
            float4 R[4];
            const float4* s4 = (const float4*)ysrc;
            #pragma unroll
            for (int r = 0; r < 4; ++r) { int idx = t + r * NT; if (idx < CHF4) R[r] = s4[idx]; }
            float4* d4 = (float4*)syA;
            #pragma unroll
            for (int r = 0; r < 4; ++r) { int idx = t + r * NT; if (idx < CHF4) d4[idx] = R[r]; }
        } else {
            for (int idx = t; idx < CH; idx += NT)
                syA[idx] = __hip_atomic_load(&ysrc[idx], __ATOMIC_RELAXED,
                                             __HIP_MEMORY_SCOPE_AGENT);
        }
        __syncthreads();

        for (int g = 0; g < NCH; ++g) {
            const float* sy = (g & 1) ? syB : syA;
            const int gn = g + 1;
            float4 R[4];
            int n4n = 0;
            if (gn < NCH) {                       // gate + issue loads for next chunk
                gate(gn, it, b, t, epoch, s_rdy);
                n4n = (gn == NCH - 1) ? LASTF4 : CHF4;
                if (!sc1mode) {
                    const float4* s4 = (const float4*)(ysrc + (size_t)gn * CH);
                    #pragma unroll
                    for (int r = 0; r < 4; ++r) { int idx = t + r * NT; if (idx < n4n) R[r] = s4[idx]; }
                }
            }
            // compute chunk g (overlaps in-flight loads)
            {
                const int key = g * N_NODES + r1;
                int e = rp2[key] + j;
                const int end = rp2[key + 1];
                for (; e < end; e += 4) {
                    int2 cc = csr[e];
                    acc1 += __int_as_float(cc.y) * sy[cc.x];
                }
            }
            if (r2 < row_end) {
                const int key = g * N_NODES + r2;
                int e = rp2[key] + j;
                const int end = rp2[key + 1];
                for (; e < end; e += 4) {
                    int2 cc = csr[e];
                    acc2 += __int_as_float(cc.y) * sy[cc.x];
                }
            }
            if (gn < NCH) {                       // write next chunk to other buffer
                float4* d4 = (float4*)((gn & 1) ? syB : syA);
                if (!sc1mode) {
                    #pragma unroll
                    for (int r = 0; r < 4; ++r) { int idx = t + r * NT; if (idx < n4n) d4[idx] = R[r]; }
                } else {
                    const float* src = ysrc + (size_t)gn * CH;
                    int chn = n4n * 4;
                    for (int idx = t; idx < chn; idx += NT)
                        d4[0] = d4[0]; // unused
                    float* df = (float*)d4;
                    for (int idx = t; idx < chn; idx += NT)
                        df[idx] = __hip_atomic_load(&src[idx], __ATOMIC_RELAXED,
                                                    __HIP_MEMORY_SCOPE_AGENT);
                }
            }
            __syncthreads();
        }

        acc1 += __shfl_xor(acc1, 1); acc1 += __shfl_xor(acc1, 2);
        acc2 += __shfl_xor(acc2, 1); acc2 += __shfl_xor(acc2, 2);
        if (j == 0) {
            __hip_atomic_store(&ydst[r1], mml(b_in[r1] + acc1),
                               __ATOMIC_RELAXED, __HIP_MEMORY_SCOPE_AGENT);
            if (r2 < row_end)
                __hip_atomic_store(&ydst[r2], mml(b_in[r2] + acc2),
                                   __ATOMIC_RELAXED, __HIP_MEMORY_SCOPE_AGENT);
        }
        __syncthreads();   // drains each wave's sc1 stores (vmcnt 0) before arrival
        if (t == 0)
            __hip_atomic_store(&arr[b], it, __ATOMIC_RELEASE,
                               __HIP_MEMORY_SCOPE_AGENT);
    }

    if (b == 1) {          // output: wait until every chunk-group reached final iter
        if (t == 0) {
            const int c = b & (NEPC - 1);
            for (int g = 0; g < NCH; ++g)
                while (__hip_atomic_load(&epoch[(g * NEPC + c) * EPST], __ATOMIC_RELAXED,
                                         __HIP_MEMORY_SCOPE_AGENT) < ITERS - 1)
                    __builtin_amdgcn_s_sleep(1);
        }
        __syncthreads();
        if (t < N_OUT) {
            const float* yfin = ybufs + (size_t)((ITERS - 1) % nbuf) * YSTR;
            out[t] = out_w[t] * __hip_atomic_load(&yfin[out_idx[t]], __ATOMIC_RELAXED,
                                                  __HIP_MEMORY_SCOPE_AGENT);
        }
    }
}

extern "C" void kernel_launch(void* const* d_in, const int* in_sizes, int n_in,
                              void* d_out, int out_size, void* d_ws, size_t ws_size,
                              hipStream_t stream) {
    const float* x      = (const float*)d_in[0];
    const float* in_w   = (const float*)d_in[1];
    const float* rec_w  = (const float*)d_in[2];
    const float* biases = (const float*)d_in[3];
    const float* out_w  = (const float*)d_in[4];
    const int*   in_idx = (const int*)d_in[5];
    const int*   e_rows = (const int*)d_in[6];
    const int*   e_cols = (const int*)d_in[7];
    const int*   out_idx= (const int*)d_in[8];
    float* out = (float*)d_out;

    char* ws = (char*)d_ws;
    float* b_in    = (float*)ws;                       // N
    int*   rp2     = (int*)(b_in + N_NODES);           // NKEYS+1 (+pad)
    int*   counts  = rp2 + (NKEYS + 64);               // NKEYS (reused as `next`)
    int*   blockSums = counts + NKEYS;                 // 1024
    int*   arr     = blockSums + 1024;                 // 256
    int*   epoch   = arr + 256;                        // NCH*NEPC*EPST = 4096
    size_t off = (size_t)((char*)(epoch + NCH * NEPC * EPST) - ws);
    off = (off + 255) & ~(size_t)255;
    int2* csr = (int2*)(ws + off);                     // N_EDGES int2 (25.6 MB)
    size_t off2 = off + (size_t)N_EDGES * sizeof(int2);
    off2 = (off2 + 255) & ~(size_t)255;
    float* ybufs = (float*)(ws + off2);                // nbuf * YSTR floats

    size_t fullA = off2 + (size_t)NBUF * YSTR * sizeof(float);
    int nbuf, sc1mode;
    if (ws_size >= fullA) { nbuf = NBUF; sc1mode = 0; }
    else                  { nbuf = 2;    sc1mode = 1; }

    hipMemsetAsync(counts, 0, NKEYS * sizeof(int), stream);
    hipMemsetAsync(arr, 0, (256 + NCH * NEPC * EPST) * sizeof(int), stream);

    k_binit<<<391, 256, 0, stream>>>(biases, b_in);
    k_scatter_in<<<1, 128, 0, stream>>>(x, in_w, in_idx, biases, b_in);
    k_y0<<<391, 256, 0, stream>>>(b_in, ybufs);        // y buffer 0 = y^(1)

    k_hist<<<1024, 256, 0, stream>>>(e_rows, e_cols, counts);
    k_scan1<<<SCAN_NBLK, SCAN_CHUNK, 0, stream>>>(counts, rp2, blockSums);
    k_scan2<<<1, 1024, 0, stream>>>(blockSums);
    k_scan3<<<SCAN_NBLK, SCAN_CHUNK, 0, stream>>>(rp2, blockSums, counts); // counts = next
    k_scatter_edges<<<1024, 256, 0, stream>>>(e_rows, e_cols, rec_w, counts, csr);

    int*   rp_a   = rp2;
    int2*  csr_a  = csr;
    float* bin_a  = b_in;
    float* yb_a   = ybufs;
    int*   arr_a  = arr;
    int*   ep_a   = epoch;
    const int*   oidx_a = out_idx;
    const float* ow_a   = out_w;
    float* out_a  = out;
    void* args[] = { &rp_a, &csr_a, &bin_a, &yb_a, &arr_a, &ep_a,
                     &oidx_a, &ow_a, &out_a, &nbuf, &sc1mode };
    hipLaunchCooperativeKernel((void*)k_iterate, dim3(NBLK), dim3(NT),
                               args, 0, stream);
}

// Round 6
// 3295.480 us; speedup vs baseline: 1.9511x; 1.9511x over previous
//
#include <hip/hip_runtime.h>

#define N_NODES 100000
#define N_EDGES 3200000
#define N_IN    128
#define N_OUT   64
#define ITERS   150
#define LEAK    0.01f

#define NT      960            // 15 waves
#define GROUPS  240            // NT/4 row-groups
#define NBW     255            // workers = blocks 1..255; block 0 = detector
#define GRID    256
#define RPB2    393            // ceil(100000/255)
#define NCH     9              // column chunks
#define CH      11520          // cols per chunk (45KB LDS); 9*11520=103680>=100000
#define CHF4    2880           // CH/4 = 3*NT  -> exactly 3 ops/thread
#define NKEYS   (NCH * N_NODES)
#define SCAN_CHUNK 1024
#define SCAN_NBLK  879         // 879*1024 >= NKEYS+1
#define NEPC    16             // replicated epoch copies per chunk-group
#define EPST    32             // ints between copies (128B)
#define YSTR    (NCH * CH)     // 103680 floats per y buffer

__device__ __forceinline__ float mml(float v) {
    v = (v < 0.0f) ? v * LEAK : v;
    if (v > 0.5f) v = 1.0f - 0.25f / v;
    return v;
}

__global__ void k_binit(const float* __restrict__ biases, float* __restrict__ b_in) {
    int i = blockIdx.x * blockDim.x + threadIdx.x;
    if (i < N_NODES) b_in[i] = biases[i];
}

// node_in.at[in_indices].set(in_w * x) -> last-write-wins for duplicates
__global__ void k_scatter_in(const float* __restrict__ x,
                             const float* __restrict__ in_w,
                             const int*   __restrict__ in_idx,
                             const float* __restrict__ biases,
                             float* __restrict__ b_in) {
    int k = threadIdx.x;
    if (k < N_IN) {
        int idx = in_idx[k];
        bool last = true;
        for (int j = k + 1; j < N_IN; ++j)
            if (in_idx[j] == idx) { last = false; break; }
        if (last) b_in[idx] = biases[idx] + in_w[k] * x[k];
    }
}

// y^(1) = act(0 + b_in)
__global__ void k_y0(const float* __restrict__ b_in, float* __restrict__ y0) {
    int i = blockIdx.x * blockDim.x + threadIdx.x;
    if (i < N_NODES) y0[i] = mml(b_in[i]);
}

// histogram over (chunk, row) buckets, chunk-major
__global__ void k_hist(const int* __restrict__ rows, const int* __restrict__ cols,
                       int* __restrict__ counts) {
    int i = blockIdx.x * blockDim.x + threadIdx.x;
    int stride = gridDim.x * blockDim.x;
    for (; i < N_EDGES; i += stride) {
        int key = (cols[i] / CH) * N_NODES + rows[i];
        atomicAdd(&counts[key], 1);
    }
}

__global__ void k_scan1(const int* __restrict__ counts, int* __restrict__ rp,
                        int* __restrict__ blockSums) {
    __shared__ int sm[SCAN_CHUNK];
    int t = threadIdx.x;
    int i = blockIdx.x * SCAN_CHUNK + t;
    int v = (i < NKEYS) ? counts[i] : 0;
    sm[t] = v;
    __syncthreads();
    for (int off = 1; off < SCAN_CHUNK; off <<= 1) {
        int add = (t >= off) ? sm[t - off] : 0;
        __syncthreads();
        sm[t] += add;
        __syncthreads();
    }
    if (i <= NKEYS) rp[i] = sm[t] - v;
    if (t == SCAN_CHUNK - 1) blockSums[blockIdx.x] = sm[t];
}

__global__ void k_scan2(int* __restrict__ blockSums) {
    __shared__ int sm[1024];
    int t = threadIdx.x;
    int v = (t < SCAN_NBLK) ? blockSums[t] : 0;
    sm[t] = v;
    __syncthreads();
    for (int off = 1; off < 1024; off <<= 1) {
        int add = (t >= off) ? sm[t - off] : 0;
        __syncthreads();
        sm[t] += add;
        __syncthreads();
    }
    if (t < SCAN_NBLK) blockSums[t] = sm[t] - v;
}

__global__ void k_scan3(int* __restrict__ rp, const int* __restrict__ blockSums,
                        int* __restrict__ next) {
    int i = blockIdx.x * SCAN_CHUNK + threadIdx.x;
    if (i <= NKEYS) {
        int val = rp[i] + blockSums[blockIdx.x];
        rp[i] = val;
        if (i < NKEYS) next[i] = val;
    }
}

// (local_col_within_chunk, weight)
__global__ void k_scatter_edges(const int* __restrict__ rows, const int* __restrict__ cols,
                                const float* __restrict__ w,
                                int* __restrict__ next, int2* __restrict__ csr) {
    int i = blockIdx.x * blockDim.x + threadIdx.x;
    int stride = gridDim.x * blockDim.x;
    for (; i < N_EDGES; i += stride) {
        int c = cols[i];
        int g = c / CH;
        int key = g * N_NODES + rows[i];
        int p = atomicAdd(&next[key], 1);
        csr[p] = make_int2(c - g * CH, __float_as_int(w[i]));
    }
}

// async 16B global->LDS staging: exactly 3 wave-ops per thread, no VGPRs held
__device__ __forceinline__ void stage_chunk(const float* __restrict__ src,
                                            float* __restrict__ dst_lds,
                                            int t, int sc1mode) {
    if (!sc1mode) {
        #pragma unroll
        for (int i = 0; i < 3; ++i) {
            const int f4 = i * NT + t;
            __builtin_amdgcn_global_load_lds(
                (const __attribute__((address_space(1))) void*)(src + (size_t)f4 * 4),
                (__attribute__((address_space(3))) void*)(dst_lds + (size_t)f4 * 4),
                16, 0, 0);
        }
    } else {
        for (int i = t; i < CH; i += NT)
            dst_lds[i] = __hip_atomic_load(&src[i], __ATOMIC_RELAXED,
                                           __HIP_MEMORY_SCOPE_AGENT);
        asm volatile("s_waitcnt lgkmcnt(0)" ::: "memory");
    }
}

__device__ __forceinline__ void gate_poll(const int* __restrict__ epoch,
                                          int c, int need, int b) {
    while (__hip_atomic_load(&epoch[(c * NEPC + (b & (NEPC - 1))) * EPST],
                             __ATOMIC_RELAXED, __HIP_MEMORY_SCOPE_AGENT) < need)
        __builtin_amdgcn_s_sleep(1);
}

// block 0 = detector (9 waves, one per chunk-group; lanes poll ~30 producers,
// wave-reconvergence aggregates, 16 replicated epoch words published).
// blocks 1..255 = workers: 9-chunk double-buffered LDS pipeline, counted
// vmcnt(3) + raw s_barrier (no vmcnt(0) drain in the steady loop).
__global__ __launch_bounds__(NT) void k_iterate(
    const int*  __restrict__ rp2,
    const int2* __restrict__ csr,
    const float* __restrict__ b_in,
    float* __restrict__ ybufs,
    int* __restrict__ arr,
    int* __restrict__ epoch,
    const int* __restrict__ out_idx,
    const float* __restrict__ out_w,
    float* __restrict__ out,
    int nbuf, int sc1mode)
{
    __shared__ float sbufA[CH], sbufB[CH];     // 2 x 45 KB
    __shared__ int   s_rp[NCH * 400];          // 14.4 KB row-pointer cache
    const int b = blockIdx.x, t = threadIdx.x;

    if (b == 0) {
        // ---------------- detector ----------------
        if (t < NCH * 64) {
            const int c = t >> 6, k = t & 63;
            int cend = (c + 1) * CH; if (cend > N_NODES) cend = N_NODES;
            const int wf = (c * CH) / RPB2;
            const int wl = (cend - 1) / RPB2;
            const int sz = wl - wf + 1;                 // <= 31
            for (int v = 1; v <= ITERS - 1; ++v) {
                if (k < sz) {
                    while (__hip_atomic_load(&arr[1 + wf + k], __ATOMIC_RELAXED,
                                             __HIP_MEMORY_SCOPE_AGENT) < v)
                        __builtin_amdgcn_s_sleep(2);
                }
                if (k < NEPC)
                    __hip_atomic_store(&epoch[(c * NEPC + k) * EPST], v,
                                       __ATOMIC_RELAXED, __HIP_MEMORY_SCOPE_AGENT);
            }
        }
        return;
    }

    // ---------------- worker ----------------
    const int wi = b - 1;
    const int row0 = wi * RPB2;
    const int row_end = (row0 + RPB2 < N_NODES) ? row0 + RPB2 : N_NODES;
    const int nrows = row_end - row0;
    const int gq = t >> 2, j = t & 3;          // 4 lanes per row
    // rotated chunk order: own groups LAST so we never gate on ourselves
    const int ord0 = ((row_end - 1) / CH + 1) % NCH;

    for (int c = 0; c < NCH; ++c)
        for (int i = t; i <= nrows; i += NT)
            s_rp[c * 400 + i] = rp2[(size_t)c * N_NODES + row0 + i];
    __syncthreads();

    // prologue: stage first chunk of it=1 (gate trivially satisfied: arr>=0)
    stage_chunk(ybufs + (size_t)ord0 * CH, sbufA, t, sc1mode);

    for (int it = 1; it <= ITERS - 1; ++it) {
        const float* ysrc = ybufs + (size_t)((it - 1) % nbuf) * YSTR;
        float*       ydst = ybufs + (size_t)(it % nbuf) * YSTR;
        float acc1 = 0.f, acc2 = 0.f;

        for (int g = 0; g < NCH; ++g) {
            const int c = (ord0 + g) % NCH;
            if (g < NCH - 1) {
                const int cn = (ord0 + g + 1) % NCH;
                if (t == 0) gate_poll(epoch, cn, it - 1, b);
                __builtin_amdgcn_s_barrier();           // gate release; also:
                asm volatile("" ::: "memory");          // compute(g-1) done -> safe overwrite
                stage_chunk(ysrc + (size_t)cn * CH,
                            ((g + 1) & 1) ? sbufB : sbufA, t, sc1mode);
                asm volatile("s_waitcnt vmcnt(3)" ::: "memory"); // chunk g landed
            } else {
                asm volatile("s_waitcnt vmcnt(0)" ::: "memory");
            }
            __builtin_amdgcn_sched_barrier(0);
            __builtin_amdgcn_s_barrier();               // all waves' chunk-g writes done
            asm volatile("" ::: "memory");

            const float* __restrict__ sy = (g & 1) ? sbufB : sbufA;
            const int base = c * 400;
            if (gq < nrows) {
                int e = s_rp[base + gq] + j;
                const int end = s_rp[base + gq + 1];
                for (; e < end; e += 4) {
                    const int2 cc = csr[e];
                    acc1 += __int_as_float(cc.y) * sy[cc.x];
                }
            }
            if (gq + GROUPS < nrows) {
                int e = s_rp[base + gq + GROUPS] + j;
                const int end = s_rp[base + gq + GROUPS + 1];
                for (; e < end; e += 4) {
                    const int2 cc = csr[e];
                    acc2 += __int_as_float(cc.y) * sy[cc.x];
                }
            }
        }

        // finalize
        acc1 += __shfl_xor(acc1, 1); acc1 += __shfl_xor(acc1, 2);
        acc2 += __shfl_xor(acc2, 1); acc2 += __shfl_xor(acc2, 2);
        if (j == 0) {
            if (gq < nrows)
                __hip_atomic_store(&ydst[row0 + gq], mml(b_in[row0 + gq] + acc1),
                                   __ATOMIC_RELAXED, __HIP_MEMORY_SCOPE_AGENT);
            if (gq + GROUPS < nrows)
                __hip_atomic_store(&ydst[row0 + gq + GROUPS],
                                   mml(b_in[row0 + gq + GROUPS] + acc2),
                                   __ATOMIC_RELAXED, __HIP_MEMORY_SCOPE_AGENT);
        }
        asm volatile("s_waitcnt vmcnt(0)" ::: "memory"); // y stores at MALL
        __builtin_amdgcn_s_barrier();                    // all waves drained
        if (t == 0)
            __hip_atomic_store(&arr[b], it, __ATOMIC_RELEASE,
                               __HIP_MEMORY_SCOPE_AGENT);

        if (it < ITERS - 1) {
            // stage first chunk of next iteration (source = y we just produced)
            if (t == 0) gate_poll(epoch, ord0, it, b);
            __builtin_amdgcn_s_barrier();
            asm volatile("" ::: "memory");
            stage_chunk(ydst + (size_t)ord0 * CH, sbufA, t, sc1mode);
        }
    }

    if (b == 1) {   // output after ALL groups reached final iteration
        if (t == 0)
            for (int c = 0; c < NCH; ++c)
                gate_poll(epoch, c, ITERS - 1, b);
        __syncthreads();
        if (t < N_OUT) {
            const float* yfin = ybufs + (size_t)((ITERS - 1) % nbuf) * YSTR;
            out[t] = out_w[t] * __hip_atomic_load(&yfin[out_idx[t]],
                       __ATOMIC_RELAXED, __HIP_MEMORY_SCOPE_AGENT);
        }
    }
}

extern "C" void kernel_launch(void* const* d_in, const int* in_sizes, int n_in,
                              void* d_out, int out_size, void* d_ws, size_t ws_size,
                              hipStream_t stream) {
    const float* x      = (const float*)d_in[0];
    const float* in_w   = (const float*)d_in[1];
    const float* rec_w  = (const float*)d_in[2];
    const float* biases = (const float*)d_in[3];
    const float* out_w  = (const float*)d_in[4];
    const int*   in_idx = (const int*)d_in[5];
    const int*   e_rows = (const int*)d_in[6];
    const int*   e_cols = (const int*)d_in[7];
    const int*   out_idx= (const int*)d_in[8];
    float* out = (float*)d_out;

    char* ws = (char*)d_ws;
    float* b_in    = (float*)ws;                       // 100000 f
    int*   rp2     = (int*)(b_in + N_NODES);           // NKEYS+1 (+pad)
    int*   blockSums = rp2 + (NKEYS + 64);             // 1024
    int*   arr     = blockSums + 1024;                 // 256
    int*   epoch   = arr + 256;                        // 9*16*32 = 4608
    int*   counts  = epoch + NCH * NEPC * EPST;        // NKEYS (also `next`)
    size_t off = (size_t)((char*)(counts + NKEYS) - ws);
    off = (off + 255) & ~(size_t)255;
    int2* csr = (int2*)(ws + off);                     // 25.6 MB
    size_t off2 = off + (size_t)N_EDGES * sizeof(int2);
    off2 = (off2 + 255) & ~(size_t)255;
    float* ybufs = (float*)(ws + off2);

    long long avail = ((long long)ws_size - (long long)off2) /
                      (long long)(YSTR * sizeof(float));
    int nbuf = (avail >= 150) ? 150 : (int)avail;
    int sc1mode = 0;
    if (nbuf < 40) { sc1mode = 1; if (nbuf > 4) nbuf = 4; }
    if (nbuf < 3) nbuf = 3;   // WAR-safety floor (gating bounds skew to 1 iter)

    hipMemsetAsync(counts, 0, NKEYS * sizeof(int), stream);
    hipMemsetAsync(arr, 0, (256 + NCH * NEPC * EPST) * sizeof(int), stream);

    k_binit<<<391, 256, 0, stream>>>(biases, b_in);
    k_scatter_in<<<1, 128, 0, stream>>>(x, in_w, in_idx, biases, b_in);
    k_y0<<<391, 256, 0, stream>>>(b_in, ybufs);        // buffer 0 = y^(1)

    k_hist<<<1024, 256, 0, stream>>>(e_rows, e_cols, counts);
    k_scan1<<<SCAN_NBLK, SCAN_CHUNK, 0, stream>>>(counts, rp2, blockSums);
    k_scan2<<<1, 1024, 0, stream>>>(blockSums);
    k_scan3<<<SCAN_NBLK, SCAN_CHUNK, 0, stream>>>(rp2, blockSums, counts);
    k_scatter_edges<<<1024, 256, 0, stream>>>(e_rows, e_cols, rec_w, counts, csr);

    int*   rp_a   = rp2;
    int2*  csr_a  = csr;
    float* bin_a  = b_in;
    float* yb_a   = ybufs;
    int*   arr_a  = arr;
    int*   ep_a   = epoch;
    const int*   oidx_a = out_idx;
    const float* ow_a   = out_w;
    float* out_a  = out;
    void* args[] = { &rp_a, &csr_a, &bin_a, &yb_a, &arr_a, &ep_a,
                     &oidx_a, &ow_a, &out_a, &nbuf, &sc1mode };
    hipLaunchCooperativeKernel((void*)k_iterate, dim3(GRID), dim3(NT),
                               args, 0, stream);
}

// Round 7
// 3203.796 us; speedup vs baseline: 2.0069x; 1.0286x over previous
//
#include <hip/hip_runtime.h>

#define N_NODES 100000
#define N_EDGES 3200000
#define N_IN    128
#define N_OUT   64
#define ITERS   150
#define LEAK    0.01f

#define NBLK    256            // all blocks compute; 1 block/CU
#define NT      960            // 15 waves
#define GROUPS  240            // NT/4 row-groups
#define RPB     391            // ceil(100000/256)
#define NCH     9              // column chunks
#define CH      11520          // cols per chunk (45KB LDS); 9*11520 = 103680
#define NKEYS   (NCH * N_NODES)
#define SCAN_CHUNK 1024
#define SCAN_NBLK  879         // 879*1024 >= NKEYS+1
#define ARRSTR  16             // ints between arrival slots (64B)
#define YSTR    (NCH * CH)     // 103680 floats per y buffer
#define NBUF    150

__device__ __forceinline__ float mml(float v) {
    v = (v < 0.0f) ? v * LEAK : v;
    if (v > 0.5f) v = 1.0f - 0.25f / v;
    return v;
}

__global__ void k_binit(const float* __restrict__ biases, float* __restrict__ b_in) {
    int i = blockIdx.x * blockDim.x + threadIdx.x;
    if (i < N_NODES) b_in[i] = biases[i];
}

// node_in.at[in_indices].set(in_w * x) -> last-write-wins for duplicates
__global__ void k_scatter_in(const float* __restrict__ x,
                             const float* __restrict__ in_w,
                             const int*   __restrict__ in_idx,
                             const float* __restrict__ biases,
                             float* __restrict__ b_in) {
    int k = threadIdx.x;
    if (k < N_IN) {
        int idx = in_idx[k];
        bool last = true;
        for (int j = k + 1; j < N_IN; ++j)
            if (in_idx[j] == idx) { last = false; break; }
        if (last) b_in[idx] = biases[idx] + in_w[k] * x[k];
    }
}

// y^(1) = act(0 + b_in)
__global__ void k_y0(const float* __restrict__ b_in, float* __restrict__ y0) {
    int i = blockIdx.x * blockDim.x + threadIdx.x;
    if (i < N_NODES) y0[i] = mml(b_in[i]);
}

// histogram over (chunk, row) buckets, chunk-major
__global__ void k_hist(const int* __restrict__ rows, const int* __restrict__ cols,
                       int* __restrict__ counts) {
    int i = blockIdx.x * blockDim.x + threadIdx.x;
    int stride = gridDim.x * blockDim.x;
    for (; i < N_EDGES; i += stride) {
        int key = (cols[i] / CH) * N_NODES + rows[i];
        atomicAdd(&counts[key], 1);
    }
}

__global__ void k_scan1(const int* __restrict__ counts, int* __restrict__ rp,
                        int* __restrict__ blockSums) {
    __shared__ int sm[SCAN_CHUNK];
    int t = threadIdx.x;
    int i = blockIdx.x * SCAN_CHUNK + t;
    int v = (i < NKEYS) ? counts[i] : 0;
    sm[t] = v;
    __syncthreads();
    for (int off = 1; off < SCAN_CHUNK; off <<= 1) {
        int add = (t >= off) ? sm[t - off] : 0;
        __syncthreads();
        sm[t] += add;
        __syncthreads();
    }
    if (i <= NKEYS) rp[i] = sm[t] - v;
    if (t == SCAN_CHUNK - 1) blockSums[blockIdx.x] = sm[t];
}

__global__ void k_scan2(int* __restrict__ blockSums) {
    __shared__ int sm[1024];
    int t = threadIdx.x;
    int v = (t < SCAN_NBLK) ? blockSums[t] : 0;
    sm[t] = v;
    __syncthreads();
    for (int off = 1; off < 1024; off <<= 1) {
        int add = (t >= off) ? sm[t - off] : 0;
        __syncthreads();
        sm[t] += add;
        __syncthreads();
    }
    if (t < SCAN_NBLK) blockSums[t] = sm[t] - v;
}

__global__ void k_scan3(int* __restrict__ rp, const int* __restrict__ blockSums,
                        int* __restrict__ next) {
    int i = blockIdx.x * SCAN_CHUNK + threadIdx.x;
    if (i <= NKEYS) {
        int val = rp[i] + blockSums[blockIdx.x];
        rp[i] = val;
        if (i < NKEYS) next[i] = val;
    }
}

// (local_col_within_chunk, weight)
__global__ void k_scatter_edges(const int* __restrict__ rows, const int* __restrict__ cols,
                                const float* __restrict__ w,
                                int* __restrict__ next, int2* __restrict__ csr) {
    int i = blockIdx.x * blockDim.x + threadIdx.x;
    int stride = gridDim.x * blockDim.x;
    for (; i < N_EDGES; i += stride) {
        int c = cols[i];
        int g = c / CH;
        int key = g * N_NODES + rows[i];
        int p = atomicAdd(&next[key], 1);
        csr[p] = make_int2(c - g * CH, __float_as_int(w[i]));
    }
}

// async 16B global->LDS: exactly 3 ops/thread, wave-uniform LDS base + lane*16
__device__ __forceinline__ void stage_chunk(const float* __restrict__ src,
                                            float* __restrict__ dst_lds, int t) {
    #pragma unroll
    for (int i = 0; i < 3; ++i) {
        const int f4 = i * NT + t;
        __builtin_amdgcn_global_load_lds(
            (const __attribute__((address_space(1))) void*)(src + (size_t)f4 * 4),
            (__attribute__((address_space(3))) void*)(dst_lds + (size_t)f4 * 4),
            16, 0, 0);
    }
}

__device__ __forceinline__ void chunk_compute(int c, const float* __restrict__ sy,
                                              const int* __restrict__ s_rp,
                                              const int2* __restrict__ csr,
                                              int gq, int j, int nrows,
                                              float& acc1, float& acc2) {
    const int base = c * 392;
    if (gq < nrows) {
        int e = s_rp[base + gq] + j;
        const int end = s_rp[base + gq + 1];
        for (; e < end; e += 4) {
            const int2 cc = csr[e];
            acc1 += __int_as_float(cc.y) * sy[cc.x];
        }
    }
    if (gq + GROUPS < nrows) {
        int e = s_rp[base + gq + GROUPS] + j;
        const int end = s_rp[base + gq + GROUPS + 1];
        for (; e < end; e += 4) {
            const int2 cc = csr[e];
            acc2 += __int_as_float(cc.y) * sy[cc.x];
        }
    }
}

// Per iteration: 9-chunk triple-buffered pipeline (ONE s_barrier + vmcnt(3)
// per chunk), then finalize + one-hop full-grid rendezvous:
//   arr[b] spread store -> 4 waves parallel-poll all 256 slots (plain agent
//   loads, distinct lines, s_sleep pacing) -> __syncthreads_and join.
// Rotating 150 y buffers keep every staged read cold-in-L2 (no fences ever).
__global__ __launch_bounds__(NT) void k_iterate(
    const int*  __restrict__ rp2,
    const int2* __restrict__ csr,
    const float* __restrict__ b_in,
    float* __restrict__ ybufs,
    int* __restrict__ arr,
    const int* __restrict__ out_idx,
    const float* __restrict__ out_w,
    float* __restrict__ out,
    int nbuf, int sc1mode)
{
    __shared__ float sb0[CH], sb1[CH], sb2[CH];   // 3 x 45KB
    __shared__ int s_rp[NCH * 392];               // 14.1KB
    const int b = blockIdx.x, t = threadIdx.x;
    const int gq = t >> 2, j = t & 3;
    const int row0 = b * RPB;
    const int row_end = (row0 + RPB < N_NODES) ? row0 + RPB : N_NODES;
    const int nrows = row_end - row0;

    // iteration-invariant row-pointer cache
    for (int c = 0; c < NCH; ++c)
        for (int i = t; i <= nrows; i += NT)
            s_rp[c * 392 + i] = rp2[(size_t)c * N_NODES + row0 + i];

    if (!sc1mode) {
        // prologue: stage c0,c1 of it=1 from buffer 0
        stage_chunk(ybufs, sb0, t);
        stage_chunk(ybufs + CH, sb1, t);
        __syncthreads();   // drains s_rp ds_writes (lgkm); stages keep flying

        for (int it = 1; it <= ITERS - 1; ++it) {
            const float* ysrc = ybufs + (size_t)((it - 1) % nbuf) * YSTR;
            float*       ydst = ybufs + (size_t)(it % nbuf) * YSTR;
            float acc1 = 0.f, acc2 = 0.f;

            #pragma unroll
            for (int g = 0; g < NCH; ++g) {
                // c_g landed: the 3 newest vmem ops are c_{g+1}'s stages
                // (in-order retirement); g=8 has no newer stage -> full drain
                if (g < NCH - 1) asm volatile("s_waitcnt vmcnt(3)" ::: "memory");
                else             asm volatile("s_waitcnt vmcnt(0)" ::: "memory");
                __builtin_amdgcn_s_barrier();   // all waves: c_g staged, c_{g-1} compute done
                const float* sy = (g % 3 == 0) ? sb0 : (g % 3 == 1) ? sb1 : sb2;
                chunk_compute(g, sy, s_rp, csr, gq, j, nrows, acc1, acc2);
                if (g + 2 < NCH) {
                    float* dst = ((g + 2) % 3 == 0) ? sb0 : ((g + 2) % 3 == 1) ? sb1 : sb2;
                    stage_chunk(ysrc + (size_t)(g + 2) * CH, dst, t);
                }
            }

            // finalize
            acc1 += __shfl_xor(acc1, 1); acc1 += __shfl_xor(acc1, 2);
            acc2 += __shfl_xor(acc2, 1); acc2 += __shfl_xor(acc2, 2);
            if (j == 0) {
                if (gq < nrows)
                    __hip_atomic_store(&ydst[row0 + gq], mml(b_in[row0 + gq] + acc1),
                                       __ATOMIC_RELAXED, __HIP_MEMORY_SCOPE_AGENT);
                if (gq + GROUPS < nrows)
                    __hip_atomic_store(&ydst[row0 + gq + GROUPS],
                                       mml(b_in[row0 + gq + GROUPS] + acc2),
                                       __ATOMIC_RELAXED, __HIP_MEMORY_SCOPE_AGENT);
            }
            asm volatile("s_waitcnt vmcnt(0)" ::: "memory");  // y at MALL
            __builtin_amdgcn_s_barrier();
            if (t == 0)
                __hip_atomic_store(&arr[b * ARRSTR], it, __ATOMIC_RELEASE,
                                   __HIP_MEMORY_SCOPE_AGENT);
            // one-hop rendezvous: 4 waves poll all 256 spread slots in parallel
            int ok;
            do {
                ok = 1;
                if (t < NBLK)
                    ok = (__hip_atomic_load(&arr[t * ARRSTR], __ATOMIC_RELAXED,
                                            __HIP_MEMORY_SCOPE_AGENT) >= it);
                if (!ok) __builtin_amdgcn_s_sleep(1);
            } while (!__syncthreads_and(ok));

            if (it < ITERS - 1) {   // stage c0,c1 of next iteration
                stage_chunk(ydst, sb0, t);
                stage_chunk(ydst + CH, sb1, t);
            }
        }
    } else {
        // -------- fallback (small ws): ping-pong + agent-load staging --------
        __syncthreads();
        for (int it = 1; it <= ITERS - 1; ++it) {
            const float* ysrc = ybufs + (size_t)((it - 1) & 1) * YSTR;
            float*       ydst = ybufs + (size_t)(it & 1) * YSTR;
            float acc1 = 0.f, acc2 = 0.f;
            for (int g = 0; g < NCH; ++g) {
                for (int i = t; i < CH; i += NT)
                    sb0[i] = __hip_atomic_load(&ysrc[(size_t)g * CH + i],
                                               __ATOMIC_RELAXED, __HIP_MEMORY_SCOPE_AGENT);
                __syncthreads();
                chunk_compute(g, sb0, s_rp, csr, gq, j, nrows, acc1, acc2);
                __syncthreads();
            }
            acc1 += __shfl_xor(acc1, 1); acc1 += __shfl_xor(acc1, 2);
            acc2 += __shfl_xor(acc2, 1); acc2 += __shfl_xor(acc2, 2);
            if (j == 0) {
                if (gq < nrows)
                    __hip_atomic_store(&ydst[row0 + gq], mml(b_in[row0 + gq] + acc1),
                                       __ATOMIC_RELAXED, __HIP_MEMORY_SCOPE_AGENT);
                if (gq + GROUPS < nrows)
                    __hip_atomic_store(&ydst[row0 + gq + GROUPS],
                                       mml(b_in[row0 + gq + GROUPS] + acc2),
                                       __ATOMIC_RELAXED, __HIP_MEMORY_SCOPE_AGENT);
            }
            __syncthreads();
            if (t == 0)
                __hip_atomic_store(&arr[b * ARRSTR], it, __ATOMIC_RELEASE,
                                   __HIP_MEMORY_SCOPE_AGENT);
            int ok;
            do {
                ok = 1;
                if (t < NBLK)
                    ok = (__hip_atomic_load(&arr[t * ARRSTR], __ATOMIC_RELAXED,
                                            __HIP_MEMORY_SCOPE_AGENT) >= it);
                if (!ok) __builtin_amdgcn_s_sleep(1);
            } while (!__syncthreads_and(ok));
        }
    }

    if (b == 0 && t < N_OUT) {
        const float* yfin = ybufs + (size_t)((ITERS - 1) % nbuf) * YSTR;
        out[t] = out_w[t] * __hip_atomic_load(&yfin[out_idx[t]],
                   __ATOMIC_RELAXED, __HIP_MEMORY_SCOPE_AGENT);
    }
}

extern "C" void kernel_launch(void* const* d_in, const int* in_sizes, int n_in,
                              void* d_out, int out_size, void* d_ws, size_t ws_size,
                              hipStream_t stream) {
    const float* x      = (const float*)d_in[0];
    const float* in_w   = (const float*)d_in[1];
    const float* rec_w  = (const float*)d_in[2];
    const float* biases = (const float*)d_in[3];
    const float* out_w  = (const float*)d_in[4];
    const int*   in_idx = (const int*)d_in[5];
    const int*   e_rows = (const int*)d_in[6];
    const int*   e_cols = (const int*)d_in[7];
    const int*   out_idx= (const int*)d_in[8];
    float* out = (float*)d_out;

    char* ws = (char*)d_ws;
    float* b_in    = (float*)ws;                       // 100000 f
    int*   rp2     = (int*)(b_in + N_NODES);           // NKEYS+1 (+pad)
    int*   blockSums = rp2 + (NKEYS + 64);             // 1024
    int*   arr     = blockSums + 1024;                 // NBLK*ARRSTR = 4096
    int*   counts  = arr + NBLK * ARRSTR;              // NKEYS (also `next`)
    size_t off = (size_t)((char*)(counts + NKEYS) - ws);
    off = (off + 255) & ~(size_t)255;
    int2* csr = (int2*)(ws + off);                     // 25.6 MB
    size_t off2 = off + (size_t)N_EDGES * sizeof(int2);
    off2 = (off2 + 255) & ~(size_t)255;
    float* ybufs = (float*)(ws + off2);

    long long avail = ((long long)ws_size - (long long)off2) /
                      (long long)(YSTR * sizeof(float));
    int nbuf, sc1mode;
    if (avail >= NBUF) { nbuf = NBUF; sc1mode = 0; }   // cold-L2 invariant needs >= ITERS
    else               { nbuf = 2;    sc1mode = 1; }

    hipMemsetAsync(counts, 0, NKEYS * sizeof(int), stream);
    hipMemsetAsync(arr, 0, NBLK * ARRSTR * sizeof(int), stream);

    k_binit<<<391, 256, 0, stream>>>(biases, b_in);
    k_scatter_in<<<1, 128, 0, stream>>>(x, in_w, in_idx, biases, b_in);
    k_y0<<<391, 256, 0, stream>>>(b_in, ybufs);        // buffer 0 = y^(1)

    k_hist<<<1024, 256, 0, stream>>>(e_rows, e_cols, counts);
    k_scan1<<<SCAN_NBLK, SCAN_CHUNK, 0, stream>>>(counts, rp2, blockSums);
    k_scan2<<<1, 1024, 0, stream>>>(blockSums);
    k_scan3<<<SCAN_NBLK, SCAN_CHUNK, 0, stream>>>(rp2, blockSums, counts);
    k_scatter_edges<<<1024, 256, 0, stream>>>(e_rows, e_cols, rec_w, counts, csr);

    int*   rp_a   = rp2;
    int2*  csr_a  = csr;
    float* bin_a  = b_in;
    float* yb_a   = ybufs;
    int*   arr_a  = arr;
    const int*   oidx_a = out_idx;
    const float* ow_a   = out_w;
    float* out_a  = out;
    void* args[] = { &rp_a, &csr_a, &bin_a, &yb_a, &arr_a,
                     &oidx_a, &ow_a, &out_a, &nbuf, &sc1mode };
    hipLaunchCooperativeKernel((void*)k_iterate, dim3(NBLK), dim3(NT),
                               args, 0, stream);
}